// Round 11
// baseline (126.992 us; speedup 1.0000x reference)
//
#include <hip/hip_runtime.h>

#define T_LEN 120000
#define LBLK 160          // samples per scan block
#define PBLK 750          // logical blocks over T (time geometry)
#define PB_USED 500       // blocks computed (only 0..499 are consumed)
#define SEG_LEN 25        // blocks per scan segment
#define NSEG_USED 20      // segment aggregates needed (blocks 0..499)
#define SEGC0 10          // first segment expanded to per-block states
#define NSEGC 11          // segments 10..20 expanded by pass2c
#define CCH 32            // t-steps per recurrence wave per chunk
#define NCHUNK 5          // chunks per block (5*32 = 160)
#define BATCH 4
#define K0 250            // first valid block (t = 40000)
#define NKV 250           // valid blocks (t in [40000, 80000))
#define DENOM 20480000.0  // 2 * 4 * 64 * 40000 (each |diff| counted twice)
#define YSTR 130          // halves per ys row: 128 ch + 2 pad (odd dword stride)

typedef _Float16 half8 __attribute__((ext_vector_type(8)));
typedef float f32x4 __attribute__((ext_vector_type(4)));

__device__ __forceinline__ float fast_tanh(float x) {
  float e = __expf(2.0f * x);
  return 1.0f - 2.0f / (e + 1.0f);
}

// Harness may store the reference's float64 coeff arrays as f64 or f32.
// Detect via a2[0] = r^2 in (0.9,1.0). Data-stable -> graph-safe; no OOB.
__device__ __forceinline__ bool coeffs_are_f64(const void* a2p) {
  double probe = *(const double*)a2p;
  return probe > 0.9 && probe < 1.0;
}
__device__ __forceinline__ double coeff_d(const void* p, bool f64, int ch) {
  return f64 ? ((const double*)p)[ch] : (double)((const float*)p)[ch];
}

// state-transition matrix A^e for A = [[-a1,-a2],[1,0]] by repeated squaring
__device__ __forceinline__ void mat_pow(double A1, double A2, int e,
                                        double& r00, double& r01,
                                        double& r10, double& r11) {
  double m00 = -A1, m01 = -A2, m10 = 1.0, m11 = 0.0;
  r00 = 1.0; r01 = 0.0; r10 = 0.0; r11 = 1.0;
  while (e) {
    if (e & 1) {
      double t00 = r00 * m00 + r01 * m10, t01 = r00 * m01 + r01 * m11;
      double t10 = r10 * m00 + r11 * m10, t11 = r10 * m01 + r11 * m11;
      r00 = t00; r01 = t01; r10 = t10; r11 = t11;
    }
    e >>= 1;
    if (e) {
      double t00 = m00 * m00 + m01 * m10, t01 = m00 * m01 + m01 * m11;
      double t10 = m10 * m00 + m11 * m10, t11 = m10 * m01 + m11 * m11;
      m00 = t00; m01 = t01; m10 = t10; m11 = t11;
    }
  }
}

// Pass 1: per (row, block) forced response with zero initial state, f32.
// 500 WGs x 4 row-quads; wave g handles row r = by*4 + g.
__global__ __launch_bounds__(256) void pass1(
    const float* __restrict__ pred, const float* __restrict__ tgt,
    const void* a1p, const void* a2p, const void* b0p,
    double* __restrict__ fbuf)
{
  int k = blockIdx.x;
  int g = threadIdx.x >> 6, lane = threadIdx.x & 63;
  int gu = __builtin_amdgcn_readfirstlane(g);
  int r = blockIdx.y * 4 + gu;
  int i = r >> 3, d = (r >> 2) & 1, b = r & 3;
  const float* sig = (i ? tgt : pred) + b * T_LEN;
  __shared__ float xs[4][LBLK];
  int base = k * LBLK;
  for (int j = lane; j < LBLK; j += 64)
    xs[gu][j] = d ? sig[T_LEN - 1 - (base + j)] : sig[base + j];
  __syncthreads();
  int ch = lane;
  bool f64 = coeffs_are_f64(a2p);
  float A1 = (float)coeff_d(a1p, f64, ch);
  float A2 = (float)coeff_d(a2p, f64, ch);
  float B0 = (float)coeff_d(b0p, f64, ch);
  float y1 = 0.0f, y2 = 0.0f;
  for (int j = 0; j < LBLK; ++j) {
    float y = fmaf(-A1, y1, fmaf(-A2, y2, B0 * xs[gu][j]));
    y2 = y1; y1 = y;
  }
  int s = r * 64 + ch;
  ((double2*)fbuf)[(size_t)k * 1024 + s] = make_double2((double)y1, (double)y2);
}

// Pass 2a: per-segment aggregate (forced response of 25 blocks, zero init),
// f64. WG 0 additionally stores per-channel A^160 and A^4000 = (A^160)^25 to
// atab (4 KB) for pass2c.
__global__ __launch_bounds__(64) void pass2a(
    const void* a1p, const void* a2p,
    const double* __restrict__ fbuf, double* __restrict__ sbuf,
    double* __restrict__ atab)
{
  int seg = blockIdx.x >> 4;
  int s = ((blockIdx.x & 15) << 6) + threadIdx.x;
  int ch = s & 63;
  bool f64 = coeffs_are_f64(a2p);
  double r00, r01, r10, r11;
  mat_pow(coeff_d(a1p, f64, ch), coeff_d(a2p, f64, ch), LBLK, r00, r01, r10, r11);
  const double2* fb = (const double2*)fbuf;
  double y1 = 0.0, y2 = 0.0;
  for (int jj = 0; jj < SEG_LEN / 5; ++jj) {
    size_t kb = (size_t)(seg * SEG_LEN + jj * 5) * 1024 + s;
    double2 f0 = fb[kb], f1 = fb[kb + 1024], f2 = fb[kb + 2048],
            f3 = fb[kb + 3072], f4 = fb[kb + 4096];
    double n1, n2;
    n1 = r00*y1 + r01*y2 + f0.x; n2 = r10*y1 + r11*y2 + f0.y; y1=n1; y2=n2;
    n1 = r00*y1 + r01*y2 + f1.x; n2 = r10*y1 + r11*y2 + f1.y; y1=n1; y2=n2;
    n1 = r00*y1 + r01*y2 + f2.x; n2 = r10*y1 + r11*y2 + f2.y; y1=n1; y2=n2;
    n1 = r00*y1 + r01*y2 + f3.x; n2 = r10*y1 + r11*y2 + f3.y; y1=n1; y2=n2;
    n1 = r00*y1 + r01*y2 + f4.x; n2 = r10*y1 + r11*y2 + f4.y; y1=n1; y2=n2;
  }
  ((double2*)sbuf)[(size_t)seg * 1024 + s] = make_double2(y1, y2);

  if (blockIdx.x == 0) {    // s = tid in [0,64): ch = tid; store A tables
    double p00 = 1.0, p01 = 0.0, p10 = 0.0, p11 = 1.0;
    double b00 = r00, b01 = r01, b10 = r10, b11 = r11;
    int e = SEG_LEN;        // (A^160)^25 = A^4000
    while (e) {
      if (e & 1) {
        double t00 = p00*b00 + p01*b10, t01 = p00*b01 + p01*b11;
        double t10 = p10*b00 + p11*b10, t11 = p10*b01 + p11*b11;
        p00 = t00; p01 = t01; p10 = t10; p11 = t11;
      }
      e >>= 1;
      if (e) {
        double t00 = b00*b00 + b01*b10, t01 = b00*b01 + b01*b11;
        double t10 = b10*b00 + b11*b10, t11 = b10*b01 + b11*b11;
        b00 = t00; b01 = t01; b10 = t10; b11 = t11;
      }
    }
    double* ap = atab + ch * 8;
    ap[0] = r00; ap[1] = r01; ap[2] = r10; ap[3] = r11;   // A^160
    ap[4] = p00; ap[5] = p01; ap[6] = p10; ap[7] = p11;   // A^4000
  }
}

// Pass 2c: expand to exact f64 per-block start states for blocks m in
// [250, 500]: stbuf[m-250] = scan state at block m start. One WG per
// (seg in [10,20], s-row): segment prefix via predicated A^4000 steps over
// sbuf (<=4 load batches), then 25 block steps (A^160 + fbuf).
__global__ __launch_bounds__(64) void pass2c(
    const double* __restrict__ fbuf, const double* __restrict__ sbuf,
    const double* __restrict__ atab, double* __restrict__ stbuf)
{
  int seg = SEGC0 + (blockIdx.x >> 4);
  int s = ((blockIdx.x & 15) << 6) + threadIdx.x;
  int ch = s & 63;
  const double2* ap = (const double2*)(atab + ch * 8);
  double2 ra = ap[0], rb = ap[1], qa = ap[2], qb = ap[3];
  double r00 = ra.x, r01 = ra.y, r10 = rb.x, r11 = rb.y;   // A^160
  double q00 = qa.x, q01 = qa.y, q10 = qb.x, q11 = qb.y;   // A^4000

  // segment prefix: predicated scan of the 20 segment aggregates
  double y1 = 0.0, y2 = 0.0;
  const double2* sb = (const double2*)sbuf;
  #pragma unroll 1
  for (int qq = 0; qq < NSEG_USED; qq += 5) {
    double2 f[5];
    #pragma unroll
    for (int p = 0; p < 5; ++p) f[p] = sb[(size_t)(qq + p) * 1024 + s];
    #pragma unroll
    for (int p = 0; p < 5; ++p) {
      if (qq + p < seg) {                 // uniform predicate
        double n1 = q00 * y1 + q01 * y2 + f[p].x;
        double n2 = q10 * y1 + q11 * y2 + f[p].y;
        y1 = n1; y2 = n2;
      }
    }
  }

  // walk the 25 blocks of this segment, writing start states
  const double2* fb = (const double2*)fbuf;
  double2* st = (double2*)stbuf;
  #pragma unroll 1
  for (int jb = 0; jb < SEG_LEN; jb += 5) {
    double2 fv[5];
    #pragma unroll
    for (int q = 0; q < 5; ++q) {
      int m = seg * SEG_LEN + jb + q;
      int mc = m < PB_USED ? m : PB_USED - 1;   // clamp (value unused OOB)
      fv[q] = fb[(size_t)mc * 1024 + s];
    }
    #pragma unroll
    for (int q = 0; q < 5; ++q) {
      int m = seg * SEG_LEN + jb + q;
      if (m <= K0 + NKV) {                      // m in [250, 500]
        st[(size_t)(m - K0) * 1024 + s] = make_double2(y1, y2);
        if (m < K0 + NKV) {
          double n1 = r00 * y1 + r01 * y2 + fv[q].x;
          double n2 = r10 * y1 + r11 * y2 + fv[q].y;
          y1 = n1; y2 = n2;
        }
      }
    }
  }
}

// Pass 3: EXACT round-8 structure (4 waves / 256 thr / full 160-block,
// s_load x, fence-free tail) with ONE change: the recurrence is 2-step
// unrolled -- (y_t, y_t+1) computed directly from (y_t-1, y_t-2) via
// companion-matrix-squared coefficients, so the dependent-FMA chain is
// 2 FMAs per 2 samples (4 cyc/sample) instead of 2 FMAs per sample.
// x-terms and LDS writes are off-chain. Coefficients derived in f64.
__global__ __launch_bounds__(256, 4) void pass3(
    const float* __restrict__ pred, const float* __restrict__ tgt,
    const void* a1p, const void* a2p, const void* b0p,
    const float* __restrict__ W, const double* __restrict__ stbuf,
    double* __restrict__ partial)
{
  int k = K0 + blockIdx.x;
  int b = blockIdx.y;
  int tid = threadIdx.x;
  __shared__ __align__(16) _Float16 ys[2][64 * YSTR]; // [buf][col(2t+i)][128ch]
  __shared__ float red[4];

  int g = tid >> 6, lane = tid & 63;
  int gu = __builtin_amdgcn_readfirstlane(g);   // wave-uniform wave id
  int iu = gu >> 1, du = gu & 1;                // uniform input / direction
  int ch = lane;
  int n0 = gu * 16;                 // wave's N-tile (16 cols = 8 t x 2 inputs)
  int lm = lane & 15, quad = lane >> 4;

  bool f64 = coeffs_are_f64(a2p);
  double A1d = coeff_d(a1p, f64, ch), A2d = coeff_d(a2p, f64, ch);
  double B0d = coeff_d(b0p, f64, ch);
  float A1 = (float)A1d, A2 = (float)A2d, B0 = (float)B0d;

  // ---- 2-step-unroll coefficients (derived in f64, cast to f32) ----
  // fwd: y_{t+1} = D1*y_{t-1} + D2*y_{t-2} + (B0*x_{t+1} + E1*x_t)
  float D1 = (float)(A1d * A1d - A2d);
  float D2 = (float)(A1d * A2d);
  float E1 = (float)(-A1d * B0d);
  // bwd: ym2 = P1*st1 + P2*st0 + Q*x;  2-step: R1*st1 + R2*st0 + Q*(P1*x0+x1)
  double P1d = -A1d / A2d, P2d = -1.0 / A2d, Qd = B0d / A2d;
  float P1 = (float)P1d, P2 = (float)P2d, Qf = (float)Qd;
  float R1 = (float)(P1d * P1d + P2d);
  float R2 = (float)(P1d * P2d);

  // ---- prologue: exact f64 block-start state, single 16B load ----
  int m = du ? (PBLK - k) : k;      // fwd: m=k in [250,500); bwd: m in (250,500]
  int s = (iu * 8 + du * 4 + b) * 64 + ch;
  double2 v0 = ((const double2*)stbuf)[(size_t)(m - K0) * 1024 + s];
  float st0 = (float)v0.x, st1 = (float)v0.y;

  // ---- W fragments: convert f32 -> f16 in registers (wave's 16-row slices) ----
  half8 wf[4][4];
  #pragma unroll
  for (int m0 = 0; m0 < 4; ++m0) {
    #pragma unroll
    for (int k0 = 0; k0 < 4; ++k0) {
      const float* wp = W + (m0 * 16 + lm) * 128 + k0 * 32 + quad * 8;
      float4 wa = *(const float4*)wp, wb = *(const float4*)(wp + 4);
      half8 h;
      h[0] = (_Float16)wa.x; h[1] = (_Float16)wa.y;
      h[2] = (_Float16)wa.z; h[3] = (_Float16)wa.w;
      h[4] = (_Float16)wb.x; h[5] = (_Float16)wb.y;
      h[6] = (_Float16)wb.z; h[7] = (_Float16)wb.w;
      wf[m0][k0] = h;
    }
  }

  // wave-uniform x pointer -> scalar loads
  const float* xp = (iu ? tgt : pred) + b * T_LEN + k * LBLK;

  float loss = 0.0f;
  for (int cc = 0; cc < NCHUNK; ++cc) {
    _Float16* yb = ys[cc & 1];
    // ---- recurrence phase (f32, uniform direction, 2-step unrolled) ----
    if (du == 0) {
      #pragma unroll
      for (int tt = 0; tt < CCH; tt += 2) {
        float x0 = xp[cc * CCH + tt];
        float x1 = xp[cc * CCH + tt + 1];
        float xa = B0 * x0;                       // off-chain
        float xb = fmaf(E1, x0, B0 * x1);         // off-chain
        float yt  = fmaf(-A1, st0, fmaf(-A2, st1, xa));  // sample tt
        float yt1 = fmaf(D1, st0, fmaf(D2, st1, xb));    // sample tt+1
        yb[(2 * tt + iu) * YSTR + ch] = (_Float16)yt;
        yb[(2 * (tt + 1) + iu) * YSTR + ch] = (_Float16)yt1;
        st1 = yt; st0 = yt1;
      }
    } else {
      #pragma unroll
      for (int tt = 0; tt < CCH; tt += 2) {
        float x0 = xp[cc * CCH + tt];
        float x1 = xp[cc * CCH + tt + 1];
        yb[(2 * tt + iu) * YSTR + 64 + ch] = (_Float16)st0;
        yb[(2 * (tt + 1) + iu) * YSTR + 64 + ch] = (_Float16)st1;
        float xc = Qf * x0;                       // off-chain
        float xd = Qf * fmaf(P1, x0, x1);         // off-chain
        float z0 = fmaf(P1, st1, fmaf(P2, st0, xc));   // state after tt
        float z1 = fmaf(R1, st1, fmaf(R2, st0, xd));   // state after tt+1
        st0 = z0; st1 = z1;
      }
    }
    __syncthreads();   // writes(buf) -> reads(buf); next writes hit other buf

    // ---- MFMA phase: wave computes z[0..63][its 16 cols] ----
    const _Float16* yrow = &yb[(n0 + lm) * YSTR + quad * 8];
    half8 bf0 = *(const half8*)(yrow);
    half8 bf1 = *(const half8*)(yrow + 32);
    half8 bf2 = *(const half8*)(yrow + 64);
    half8 bf3 = *(const half8*)(yrow + 96);
    #pragma unroll
    for (int m0 = 0; m0 < 4; ++m0) {
      f32x4 c = {0.f, 0.f, 0.f, 0.f};
      c = __builtin_amdgcn_mfma_f32_16x16x32_f16(wf[m0][0], bf0, c, 0, 0, 0);
      c = __builtin_amdgcn_mfma_f32_16x16x32_f16(wf[m0][1], bf1, c, 0, 0, 0);
      c = __builtin_amdgcn_mfma_f32_16x16x32_f16(wf[m0][2], bf2, c, 0, 0, 0);
      c = __builtin_amdgcn_mfma_f32_16x16x32_f16(wf[m0][3], bf3, c, 0, 0, 0);
      #pragma unroll
      for (int r = 0; r < 4; ++r) {
        float vv = fast_tanh(c[r]);
        float p = __shfl_xor(vv, 1);   // partner col = other input, same t
        loss += fabsf(vv - p);
      }
    }
  }

  // block reduction -> one plain double store per workgroup
  #pragma unroll
  for (int off = 32; off > 0; off >>= 1) loss += __shfl_down(loss, off);
  if (lane == 0) red[g] = loss;
  __syncthreads();
  if (tid == 0)
    partial[b * NKV + blockIdx.x] =
        (double)((red[0] + red[1]) + (red[2] + red[3]));
}

// Finalize: one WG reduces the 1000 partials -> out.
__global__ __launch_bounds__(256) void finalize(
    const double* __restrict__ partial, float* __restrict__ out)
{
  __shared__ double dred[4];
  int tid = threadIdx.x, lane = tid & 63, g = tid >> 6;
  double v = partial[tid] + partial[tid + 256] + partial[tid + 512];
  if (tid + 768 < NKV * BATCH) v += partial[tid + 768];
  #pragma unroll
  for (int off = 32; off > 0; off >>= 1) v += __shfl_down(v, off);
  if (lane == 0) dred[g] = v;
  __syncthreads();
  if (tid == 0)
    out[0] = (float)(((dred[0] + dred[1]) + (dred[2] + dred[3])) / DENOM);
}

extern "C" void kernel_launch(void* const* d_in, const int* in_sizes, int n_in,
                              void* d_out, int out_size, void* d_ws, size_t ws_size,
                              hipStream_t stream) {
  const float* pred = (const float*)d_in[0];
  const float* tgt  = (const float*)d_in[1];
  const void* a1p = d_in[2];
  const void* a2p = d_in[3];
  const void* b0p = d_in[4];
  const float* W  = (const float*)d_in[5];
  float* out = (float*)d_out;

  double* base = (double*)d_ws;
  double* fbuf = base;                                // [500][1024][2]
  double* sbuf = fbuf + (size_t)PB_USED * 1024 * 2;   // [20][1024][2] (pad 32)
  double* atab = sbuf + (size_t)32 * 1024 * 2;        // [64][8] (pad 512 dbl)
  double* stbuf = atab + 512;                         // [251][1024][2]
  double* partial = stbuf + (size_t)(NKV + 1) * 1024 * 2;  // [1000]

  pass1<<<dim3(PB_USED, 4), 256, 0, stream>>>(pred, tgt, a1p, a2p, b0p, fbuf);
  pass2a<<<NSEG_USED * 16, 64, 0, stream>>>(a1p, a2p, fbuf, sbuf, atab);
  pass2c<<<NSEGC * 16, 64, 0, stream>>>(fbuf, sbuf, atab, stbuf);
  pass3<<<dim3(NKV, BATCH), 256, 0, stream>>>(pred, tgt, a1p, a2p, b0p,
                                              W, stbuf, partial);
  finalize<<<1, 256, 0, stream>>>(partial, out);
}

// Round 12
// 121.013 us; speedup vs baseline: 1.0494x; 1.0494x over previous
//
#include <hip/hip_runtime.h>

#define T_LEN 120000
#define LBLK 160          // samples per scan block
#define PBLK 750          // logical blocks over T (time geometry)
#define PB_USED 500       // blocks computed (only 0..499 are consumed)
#define SEG_LEN 25        // blocks per scan segment
#define NSEG_USED 20      // segment aggregates needed (blocks 0..499)
#define SEGC0 10          // first segment expanded to per-block states
#define NSEGC 11          // segments 10..20 expanded by pass2c
#define CCH 32            // t-steps per recurrence wave per chunk
#define NCHUNK 5          // chunks per block (5*32 = 160)
#define BATCH 4
#define K0 250            // first valid block (t = 40000)
#define NKV 250           // valid blocks (t in [40000, 80000))
#define DENOM 20480000.0  // 2 * 4 * 64 * 40000 (each |diff| counted twice)
#define YSTR 130          // halves per ys row: 128 ch + 2 pad (odd dword stride)

typedef _Float16 half8 __attribute__((ext_vector_type(8)));
typedef float f32x4 __attribute__((ext_vector_type(4)));

__device__ __forceinline__ float fast_tanh(float x) {
  float e = __expf(2.0f * x);
  return 1.0f - 2.0f / (e + 1.0f);
}

// Harness may store the reference's float64 coeff arrays as f64 or f32.
// Detect via a2[0] = r^2 in (0.9,1.0). Data-stable -> graph-safe; no OOB.
__device__ __forceinline__ bool coeffs_are_f64(const void* a2p) {
  double probe = *(const double*)a2p;
  return probe > 0.9 && probe < 1.0;
}
__device__ __forceinline__ double coeff_d(const void* p, bool f64, int ch) {
  return f64 ? ((const double*)p)[ch] : (double)((const float*)p)[ch];
}

// state-transition matrix A^e for A = [[-a1,-a2],[1,0]] by repeated squaring
__device__ __forceinline__ void mat_pow(double A1, double A2, int e,
                                        double& r00, double& r01,
                                        double& r10, double& r11) {
  double m00 = -A1, m01 = -A2, m10 = 1.0, m11 = 0.0;
  r00 = 1.0; r01 = 0.0; r10 = 0.0; r11 = 1.0;
  while (e) {
    if (e & 1) {
      double t00 = r00 * m00 + r01 * m10, t01 = r00 * m01 + r01 * m11;
      double t10 = r10 * m00 + r11 * m10, t11 = r10 * m01 + r11 * m11;
      r00 = t00; r01 = t01; r10 = t10; r11 = t11;
    }
    e >>= 1;
    if (e) {
      double t00 = m00 * m00 + m01 * m10, t01 = m00 * m01 + m01 * m11;
      double t10 = m10 * m00 + m11 * m10, t11 = m10 * m01 + m11 * m11;
      m00 = t00; m01 = t01; m10 = t10; m11 = t11;
    }
  }
}

// Pass 1: per (row, block) forced response with zero initial state, f32.
// 500 WGs x 4 row-quads; wave g handles row r = by*4 + g.
__global__ __launch_bounds__(256) void pass1(
    const float* __restrict__ pred, const float* __restrict__ tgt,
    const void* a1p, const void* a2p, const void* b0p,
    double* __restrict__ fbuf)
{
  int k = blockIdx.x;
  int g = threadIdx.x >> 6, lane = threadIdx.x & 63;
  int gu = __builtin_amdgcn_readfirstlane(g);
  int r = blockIdx.y * 4 + gu;
  int i = r >> 3, d = (r >> 2) & 1, b = r & 3;
  const float* sig = (i ? tgt : pred) + b * T_LEN;
  __shared__ float xs[4][LBLK];
  int base = k * LBLK;
  for (int j = lane; j < LBLK; j += 64)
    xs[gu][j] = d ? sig[T_LEN - 1 - (base + j)] : sig[base + j];
  __syncthreads();
  int ch = lane;
  bool f64 = coeffs_are_f64(a2p);
  float A1 = (float)coeff_d(a1p, f64, ch);
  float A2 = (float)coeff_d(a2p, f64, ch);
  float B0 = (float)coeff_d(b0p, f64, ch);
  float y1 = 0.0f, y2 = 0.0f;
  for (int j = 0; j < LBLK; ++j) {
    float y = fmaf(-A1, y1, fmaf(-A2, y2, B0 * xs[gu][j]));
    y2 = y1; y1 = y;
  }
  int s = r * 64 + ch;
  ((double2*)fbuf)[(size_t)k * 1024 + s] = make_double2((double)y1, (double)y2);
}

// Pass 2a: per-segment aggregate (forced response of 25 blocks, zero init),
// f64. WG 0 additionally stores per-channel A^160 and A^4000 = (A^160)^25 to
// atab (4 KB) for pass2c.
__global__ __launch_bounds__(64) void pass2a(
    const void* a1p, const void* a2p,
    const double* __restrict__ fbuf, double* __restrict__ sbuf,
    double* __restrict__ atab)
{
  int seg = blockIdx.x >> 4;
  int s = ((blockIdx.x & 15) << 6) + threadIdx.x;
  int ch = s & 63;
  bool f64 = coeffs_are_f64(a2p);
  double r00, r01, r10, r11;
  mat_pow(coeff_d(a1p, f64, ch), coeff_d(a2p, f64, ch), LBLK, r00, r01, r10, r11);
  const double2* fb = (const double2*)fbuf;
  double y1 = 0.0, y2 = 0.0;
  for (int jj = 0; jj < SEG_LEN / 5; ++jj) {
    size_t kb = (size_t)(seg * SEG_LEN + jj * 5) * 1024 + s;
    double2 f0 = fb[kb], f1 = fb[kb + 1024], f2 = fb[kb + 2048],
            f3 = fb[kb + 3072], f4 = fb[kb + 4096];
    double n1, n2;
    n1 = r00*y1 + r01*y2 + f0.x; n2 = r10*y1 + r11*y2 + f0.y; y1=n1; y2=n2;
    n1 = r00*y1 + r01*y2 + f1.x; n2 = r10*y1 + r11*y2 + f1.y; y1=n1; y2=n2;
    n1 = r00*y1 + r01*y2 + f2.x; n2 = r10*y1 + r11*y2 + f2.y; y1=n1; y2=n2;
    n1 = r00*y1 + r01*y2 + f3.x; n2 = r10*y1 + r11*y2 + f3.y; y1=n1; y2=n2;
    n1 = r00*y1 + r01*y2 + f4.x; n2 = r10*y1 + r11*y2 + f4.y; y1=n1; y2=n2;
  }
  ((double2*)sbuf)[(size_t)seg * 1024 + s] = make_double2(y1, y2);

  if (blockIdx.x == 0) {    // s = tid in [0,64): ch = tid; store A tables
    double p00 = 1.0, p01 = 0.0, p10 = 0.0, p11 = 1.0;
    double b00 = r00, b01 = r01, b10 = r10, b11 = r11;
    int e = SEG_LEN;        // (A^160)^25 = A^4000
    while (e) {
      if (e & 1) {
        double t00 = p00*b00 + p01*b10, t01 = p00*b01 + p01*b11;
        double t10 = p10*b00 + p11*b10, t11 = p10*b01 + p11*b11;
        p00 = t00; p01 = t01; p10 = t10; p11 = t11;
      }
      e >>= 1;
      if (e) {
        double t00 = b00*b00 + b01*b10, t01 = b00*b01 + b01*b11;
        double t10 = b10*b00 + b11*b10, t11 = b10*b01 + b11*b11;
        b00 = t00; b01 = t01; b10 = t10; b11 = t11;
      }
    }
    double* ap = atab + ch * 8;
    ap[0] = r00; ap[1] = r01; ap[2] = r10; ap[3] = r11;   // A^160
    ap[4] = p00; ap[5] = p01; ap[6] = p10; ap[7] = p11;   // A^4000
  }
}

// Pass 2c: expand to exact f64 per-block start states for blocks m in
// [250, 500]: stbuf[m-250] = scan state at block m start. One WG per
// (seg in [10,20], s-row): segment prefix via predicated A^4000 steps over
// sbuf (<=4 load batches), then 25 block steps (A^160 + fbuf).
__global__ __launch_bounds__(64) void pass2c(
    const double* __restrict__ fbuf, const double* __restrict__ sbuf,
    const double* __restrict__ atab, double* __restrict__ stbuf)
{
  int seg = SEGC0 + (blockIdx.x >> 4);
  int s = ((blockIdx.x & 15) << 6) + threadIdx.x;
  int ch = s & 63;
  const double2* ap = (const double2*)(atab + ch * 8);
  double2 ra = ap[0], rb = ap[1], qa = ap[2], qb = ap[3];
  double r00 = ra.x, r01 = ra.y, r10 = rb.x, r11 = rb.y;   // A^160
  double q00 = qa.x, q01 = qa.y, q10 = qb.x, q11 = qb.y;   // A^4000

  // segment prefix: predicated scan of the 20 segment aggregates
  double y1 = 0.0, y2 = 0.0;
  const double2* sb = (const double2*)sbuf;
  #pragma unroll 1
  for (int qq = 0; qq < NSEG_USED; qq += 5) {
    double2 f[5];
    #pragma unroll
    for (int p = 0; p < 5; ++p) f[p] = sb[(size_t)(qq + p) * 1024 + s];
    #pragma unroll
    for (int p = 0; p < 5; ++p) {
      if (qq + p < seg) {                 // uniform predicate
        double n1 = q00 * y1 + q01 * y2 + f[p].x;
        double n2 = q10 * y1 + q11 * y2 + f[p].y;
        y1 = n1; y2 = n2;
      }
    }
  }

  // walk the 25 blocks of this segment, writing start states
  const double2* fb = (const double2*)fbuf;
  double2* st = (double2*)stbuf;
  #pragma unroll 1
  for (int jb = 0; jb < SEG_LEN; jb += 5) {
    double2 fv[5];
    #pragma unroll
    for (int q = 0; q < 5; ++q) {
      int m = seg * SEG_LEN + jb + q;
      int mc = m < PB_USED ? m : PB_USED - 1;   // clamp (value unused OOB)
      fv[q] = fb[(size_t)mc * 1024 + s];
    }
    #pragma unroll
    for (int q = 0; q < 5; ++q) {
      int m = seg * SEG_LEN + jb + q;
      if (m <= K0 + NKV) {                      // m in [250, 500]
        st[(size_t)(m - K0) * 1024 + s] = make_double2(y1, y2);
        if (m < K0 + NKV) {
          double n1 = r00 * y1 + r01 * y2 + fv[q].x;
          double n2 = r10 * y1 + r11 * y2 + fv[q].y;
          y1 = n1; y2 = n2;
        }
      }
    }
  }
}

// Pass 3: per (valid block k, batch b). Round-8-verified configuration --
// the empirical optimum across 7 tested variants (4 waves / 256 thr / full
// 160-block / s_load x / 1-step recurrence / fence-free tail). Prologue is a
// single 16B stbuf load (exact f64 block-start state). Then f32 in-block
// recurrence -> f16 Y in LDS (double-buffered) -> MFMA 16x16x32_f16 -> tanh
// -> |p-t| reduce -> plain partial store.
__global__ __launch_bounds__(256, 4) void pass3(
    const float* __restrict__ pred, const float* __restrict__ tgt,
    const void* a1p, const void* a2p, const void* b0p,
    const float* __restrict__ W, const double* __restrict__ stbuf,
    double* __restrict__ partial)
{
  int k = K0 + blockIdx.x;
  int b = blockIdx.y;
  int tid = threadIdx.x;
  __shared__ __align__(16) _Float16 ys[2][64 * YSTR]; // [buf][col(2t+i)][128ch]
  __shared__ float red[4];

  int g = tid >> 6, lane = tid & 63;
  int gu = __builtin_amdgcn_readfirstlane(g);   // wave-uniform wave id
  int iu = gu >> 1, du = gu & 1;                // uniform input / direction
  int ch = lane;
  int n0 = gu * 16;                 // wave's N-tile (16 cols = 8 t x 2 inputs)
  int lm = lane & 15, quad = lane >> 4;

  bool f64 = coeffs_are_f64(a2p);
  double A1d = coeff_d(a1p, f64, ch), A2d = coeff_d(a2p, f64, ch);
  double B0d = coeff_d(b0p, f64, ch);
  float A1 = (float)A1d, A2 = (float)A2d, B0 = (float)B0d;
  float IA2 = (float)(1.0 / A2d);

  // ---- prologue: exact f64 block-start state, single 16B load ----
  int m = du ? (PBLK - k) : k;      // fwd: m=k in [250,500); bwd: m in (250,500]
  int s = (iu * 8 + du * 4 + b) * 64 + ch;
  double2 v0 = ((const double2*)stbuf)[(size_t)(m - K0) * 1024 + s];
  float st0 = (float)v0.x, st1 = (float)v0.y;

  // ---- W fragments: convert f32 -> f16 in registers (wave's 16-row slices) ----
  half8 wf[4][4];
  #pragma unroll
  for (int m0 = 0; m0 < 4; ++m0) {
    #pragma unroll
    for (int k0 = 0; k0 < 4; ++k0) {
      const float* wp = W + (m0 * 16 + lm) * 128 + k0 * 32 + quad * 8;
      float4 wa = *(const float4*)wp, wb = *(const float4*)(wp + 4);
      half8 h;
      h[0] = (_Float16)wa.x; h[1] = (_Float16)wa.y;
      h[2] = (_Float16)wa.z; h[3] = (_Float16)wa.w;
      h[4] = (_Float16)wb.x; h[5] = (_Float16)wb.y;
      h[6] = (_Float16)wb.z; h[7] = (_Float16)wb.w;
      wf[m0][k0] = h;
    }
  }

  // wave-uniform x pointer -> scalar loads
  const float* xp = (iu ? tgt : pred) + b * T_LEN + k * LBLK;

  float loss = 0.0f;
  for (int cc = 0; cc < NCHUNK; ++cc) {
    _Float16* yb = ys[cc & 1];
    // ---- recurrence phase (f32, uniform direction, scalar x) ----
    if (du == 0) {
      #pragma unroll
      for (int tt = 0; tt < CCH; ++tt) {
        float x = xp[cc * CCH + tt];
        float y = fmaf(-A1, st0, fmaf(-A2, st1, B0 * x));
        yb[(2 * tt + iu) * YSTR + ch] = (_Float16)y;
        st1 = st0; st0 = y;
      }
    } else {
      #pragma unroll
      for (int tt = 0; tt < CCH; ++tt) {
        float x = xp[cc * CCH + tt];
        yb[(2 * tt + iu) * YSTR + 64 + ch] = (_Float16)st0;
        float ym2 = (fmaf(-A1, st1, B0 * x) - st0) * IA2;
        st0 = st1; st1 = ym2;
      }
    }
    __syncthreads();   // writes(buf) -> reads(buf); next writes hit other buf

    // ---- MFMA phase: wave computes z[0..63][its 16 cols] ----
    const _Float16* yrow = &yb[(n0 + lm) * YSTR + quad * 8];
    half8 bf0 = *(const half8*)(yrow);
    half8 bf1 = *(const half8*)(yrow + 32);
    half8 bf2 = *(const half8*)(yrow + 64);
    half8 bf3 = *(const half8*)(yrow + 96);
    #pragma unroll
    for (int m0 = 0; m0 < 4; ++m0) {
      f32x4 c = {0.f, 0.f, 0.f, 0.f};
      c = __builtin_amdgcn_mfma_f32_16x16x32_f16(wf[m0][0], bf0, c, 0, 0, 0);
      c = __builtin_amdgcn_mfma_f32_16x16x32_f16(wf[m0][1], bf1, c, 0, 0, 0);
      c = __builtin_amdgcn_mfma_f32_16x16x32_f16(wf[m0][2], bf2, c, 0, 0, 0);
      c = __builtin_amdgcn_mfma_f32_16x16x32_f16(wf[m0][3], bf3, c, 0, 0, 0);
      #pragma unroll
      for (int r = 0; r < 4; ++r) {
        float vv = fast_tanh(c[r]);
        float p = __shfl_xor(vv, 1);   // partner col = other input, same t
        loss += fabsf(vv - p);
      }
    }
  }

  // block reduction -> one plain double store per workgroup
  #pragma unroll
  for (int off = 32; off > 0; off >>= 1) loss += __shfl_down(loss, off);
  if (lane == 0) red[g] = loss;
  __syncthreads();
  if (tid == 0)
    partial[b * NKV + blockIdx.x] =
        (double)((red[0] + red[1]) + (red[2] + red[3]));
}

// Finalize: one WG reduces the 1000 partials -> out.
__global__ __launch_bounds__(256) void finalize(
    const double* __restrict__ partial, float* __restrict__ out)
{
  __shared__ double dred[4];
  int tid = threadIdx.x, lane = tid & 63, g = tid >> 6;
  double v = partial[tid] + partial[tid + 256] + partial[tid + 512];
  if (tid + 768 < NKV * BATCH) v += partial[tid + 768];
  #pragma unroll
  for (int off = 32; off > 0; off >>= 1) v += __shfl_down(v, off);
  if (lane == 0) dred[g] = v;
  __syncthreads();
  if (tid == 0)
    out[0] = (float)(((dred[0] + dred[1]) + (dred[2] + dred[3])) / DENOM);
}

extern "C" void kernel_launch(void* const* d_in, const int* in_sizes, int n_in,
                              void* d_out, int out_size, void* d_ws, size_t ws_size,
                              hipStream_t stream) {
  const float* pred = (const float*)d_in[0];
  const float* tgt  = (const float*)d_in[1];
  const void* a1p = d_in[2];
  const void* a2p = d_in[3];
  const void* b0p = d_in[4];
  const float* W  = (const float*)d_in[5];
  float* out = (float*)d_out;

  double* base = (double*)d_ws;
  double* fbuf = base;                                // [500][1024][2]
  double* sbuf = fbuf + (size_t)PB_USED * 1024 * 2;   // [20][1024][2] (pad 32)
  double* atab = sbuf + (size_t)32 * 1024 * 2;        // [64][8] (pad 512 dbl)
  double* stbuf = atab + 512;                         // [251][1024][2]
  double* partial = stbuf + (size_t)(NKV + 1) * 1024 * 2;  // [1000]

  pass1<<<dim3(PB_USED, 4), 256, 0, stream>>>(pred, tgt, a1p, a2p, b0p, fbuf);
  pass2a<<<NSEG_USED * 16, 64, 0, stream>>>(a1p, a2p, fbuf, sbuf, atab);
  pass2c<<<NSEGC * 16, 64, 0, stream>>>(fbuf, sbuf, atab, stbuf);
  pass3<<<dim3(NKV, BATCH), 256, 0, stream>>>(pred, tgt, a1p, a2p, b0p,
                                              W, stbuf, partial);
  finalize<<<1, 256, 0, stream>>>(partial, out);
}